// Round 4
// baseline (313.561 us; speedup 1.0000x reference)
//
#include <hip/hip_runtime.h>
#include <hip/hip_bf16.h>
#include <math.h>

// Problem constants
#define NB   32
#define CIN  256
#define HH   64
#define WW   64
#define ICK  768     // 3*CIN
#define MIPC 8
#define PP   128     // h + w

__device__ __forceinline__ float sigmoidf_(float v) {
    return 1.0f / (1.0f + expf(-v));
}

// ---------------- Kernel 1: pooled stats -> yin[n][768][128] ----------------
// block per (n, c). Loads 64x64 f32 tile, computes row half-sums and column
// half-sums, writes the 6 pooled groups in conv-input layout.
__global__ void k1_pool(const float* __restrict__ x, float* __restrict__ yin) {
    const int n = blockIdx.x >> 8;
    const int c = blockIdx.x & 255;
    __shared__ float tile[64][65];   // +1 pad: conflict-free column reads
    __shared__ float rs[64][2];      // row half-sums (w<32, w>=32)
    __shared__ float cs[2][64];      // col half-sums (h<32, h>=32)

    const int t = threadIdx.x;
    const float* xb = x + ((size_t)(n * CIN + c) << 12);   // 4096 floats

    const float4* x4 = (const float4*)xb;
#pragma unroll
    for (int i = 0; i < 4; ++i) {
        int idx  = i * 256 + t;        // float4 index 0..1023
        int row  = idx >> 4;
        int col4 = idx & 15;
        float4 v = x4[idx];
        tile[row][col4 * 4 + 0] = v.x;
        tile[row][col4 * 4 + 1] = v.y;
        tile[row][col4 * 4 + 2] = v.z;
        tile[row][col4 * 4 + 3] = v.w;
    }
    __syncthreads();

    if (t < 128) {
        int r = t >> 1, half = t & 1;
        float s = 0.f;
#pragma unroll
        for (int j = 0; j < 32; ++j) s += tile[r][half * 32 + j];
        rs[r][half] = s;
    } else {
        int t2 = t - 128;
        int w = t2 & 63, hh = t2 >> 6;
        float s = 0.f;
#pragma unroll
        for (int j = 0; j < 32; ++j) s += tile[hh * 32 + j][w];
        cs[hh][w] = s;
    }
    __syncthreads();

    if (t < 128) {
        int p = t;
        float g1, g2;
        if (p < 64) { g1 = rs[p][0];      g2 = rs[p][1]; }
        else        { g1 = cs[0][p - 64]; g2 = cs[1][p - 64]; }
        float g0 = (g1 + g2) * (1.f / 64.f);
        float* yb = yin + ((size_t)n * ICK + c) * PP + p;
        yb[0]                      = g0;
        yb[(size_t)256 * PP]       = g1 * (1.f / 32.f);
        yb[(size_t)512 * PP]       = g2 * (1.f / 32.f);
    }
}

// ---- Kernel 2: 1-D dilated conv (center kw tap) + BN + SiLU + SE gate ----
// grid (n, o) = 256 blocks. SE mean is per-(n,o) over the 128 positions, so
// the gate is block-local. Writes pre-gated ygated[n][8][128].
__global__ void __launch_bounds__(256)
k2_conv(const float* __restrict__ yin, const float* __restrict__ w1,
        const float* __restrict__ b1,
        const float* __restrict__ gamma, const float* __restrict__ beta,
        const float* __restrict__ bmean, const float* __restrict__ bvar,
        const float* __restrict__ gw, const float* __restrict__ gb,
        float* __restrict__ ygated) {
    const int n = blockIdx.x >> 3;
    const int o = blockIdx.x & 7;
    const int t = threadIdx.x;

    __shared__ float Wl[ICK * 3];    // 9.2 KB: kw=1 column of the 3x3 kernel
    __shared__ float part[2][128];
    __shared__ float red[2];
    __shared__ float gateS;

    for (int i = t; i < ICK * 3; i += 256) {
        int ic = i / 3, kh = i - ic * 3;
        Wl[i] = w1[(size_t)o * (ICK * 9) + (size_t)ic * 9 + kh * 3 + 1];
    }
    __syncthreads();

    const int p   = t & 127;
    const int rep = t >> 7;
    const float* yb = yin + ((size_t)n * ICK + rep * 384) * PP;

    float a0 = 0.f, a1 = 0.f, a2 = 0.f, a3 = 0.f;
#pragma unroll 4
    for (int i = 0; i < 384; ++i) {
        const float* row = yb + (size_t)i * PP;
        const float* wr  = &Wl[(rep * 384 + i) * 3];
        float v0 = (p >= 2)   ? row[p - 2] : 0.f;
        float v1 = row[p];
        float v2 = (p < 126) ? row[p + 2] : 0.f;
        a0 += wr[0] * v0;
        a1 += wr[1] * v1;
        a2 += wr[2] * v2;
        a3 += 0.f;   // keeps 4-acc shape trivially; folded below
    }
    float acc = (a0 + a1) + (a2 + a3);

    part[rep][p] = acc;
    __syncthreads();

    float s = 0.f;
    if (t < 128) {
        float tot = part[0][t] + part[1][t];
        float scale = gamma[o] * rsqrtf(bvar[o] + 1e-5f);
        float v = (tot + b1[o] - bmean[o]) * scale + beta[o];
        s = v * sigmoidf_(v);
    }
    // mean over the 128 valid lanes (waves 0,1); waves 2,3 contribute 0
    float v = s;
#pragma unroll
    for (int off = 32; off; off >>= 1) v += __shfl_down(v, off);
    if ((t & 63) == 0) red[t >> 6] = v;
    __syncthreads();
    if (t == 0) {
        float mean = (red[0] + red[1]) * (1.f / 128.f);
        gateS = sigmoidf_(gw[0] * mean + gb[0]);
    }
    __syncthreads();
    if (t < 128) {
        ygated[((size_t)n * MIPC + o) * PP + t] = s * gateS;
    }
}

// ------- Kernel 3: heads (a_h, a_w from ygated) + out = x * a_h * a_w -------
// block per (n, c). ygated slice (4 KB) is L2-broadcast to all 256 c-blocks.
__global__ void __launch_bounds__(256)
k3_apply(const float* __restrict__ x, const float* __restrict__ ygated,
         const float* __restrict__ chw, const float* __restrict__ chb,
         const float* __restrict__ cww, const float* __restrict__ cwb,
         float* __restrict__ out) {
    const int n = blockIdx.x >> 8;
    const int c = blockIdx.x & 255;
    const int t = threadIdx.x;
    __shared__ float yg[MIPC * PP];  // 1024 floats
    __shared__ float ah[64];
    __shared__ float aw[64];

    ((float4*)yg)[t] = ((const float4*)(ygated + (size_t)n * MIPC * PP))[t];
    __syncthreads();

    if (t < 64) {
        float a = chb[c];
#pragma unroll
        for (int m = 0; m < MIPC; ++m) a += chw[c * MIPC + m] * yg[m * PP + t];
        ah[t] = sigmoidf_(a);
    } else if (t < 128) {
        int h = t - 64;
        float a = cwb[c];
#pragma unroll
        for (int m = 0; m < MIPC; ++m) a += cww[c * MIPC + m] * yg[m * PP + 64 + h];
        aw[h] = sigmoidf_(a);
    }
    __syncthreads();

    size_t base = ((size_t)(n * CIN + c)) << 12;
    const float4* x4 = (const float4*)(x + base);
    float4* o4 = (float4*)(out + base);
    const float4* aw4 = (const float4*)aw;
#pragma unroll
    for (int i = 0; i < 4; ++i) {
        int idx  = i * 256 + t;
        int row  = idx >> 4;
        int col4 = idx & 15;
        float4 v = x4[idx];
        float a = ah[row];
        float4 wv = aw4[col4];
        v.x *= a * wv.x;
        v.y *= a * wv.y;
        v.z *= a * wv.z;
        v.w *= a * wv.w;
        o4[idx] = v;
    }
}

extern "C" void kernel_launch(void* const* d_in, const int* in_sizes, int n_in,
                              void* d_out, int out_size, void* d_ws, size_t ws_size,
                              hipStream_t stream) {
    const float* x     = (const float*)d_in[0];
    const float* w1    = (const float*)d_in[1];
    const float* b1    = (const float*)d_in[2];
    const float* gamma = (const float*)d_in[3];
    const float* beta  = (const float*)d_in[4];
    const float* bmean = (const float*)d_in[5];
    const float* bvar  = (const float*)d_in[6];
    const float* gw    = (const float*)d_in[7];
    const float* gb    = (const float*)d_in[8];
    const float* chw   = (const float*)d_in[9];
    const float* chb   = (const float*)d_in[10];
    const float* cww   = (const float*)d_in[11];
    const float* cwb   = (const float*)d_in[12];
    float* out = (float*)d_out;

    float* ws     = (float*)d_ws;
    float* yin    = ws;                              // 32*768*128 = 3,145,728 f
    float* ygated = yin + (size_t)NB * ICK * PP;     // 32*8*128   = 32,768 f

    k1_pool <<<NB * CIN, 256, 0, stream>>>(x, yin);
    k2_conv <<<NB * MIPC, 256, 0, stream>>>(yin, w1, b1, gamma, beta, bmean, bvar,
                                            gw, gb, ygated);
    k3_apply<<<NB * CIN, 256, 0, stream>>>(x, ygated, chw, chb, cww, cwb, out);
}

// Round 5
// 286.647 us; speedup vs baseline: 1.0939x; 1.0939x over previous
//
#include <hip/hip_runtime.h>
#include <hip/hip_bf16.h>
#include <math.h>

// Problem constants
#define NB   32
#define CIN  256
#define HH   64
#define WW   64
#define ICK  768     // 3*CIN
#define MIPC 8
#define PP   128     // h + w

__device__ __forceinline__ float sigmoidf_(float v) {
    return 1.0f / (1.0f + expf(-v));
}

// ---------------- Kernel 1: pooled stats -> yin[n][768][128] ----------------
// block per (n, c). Loads 64x64 f32 tile, computes row half-sums and column
// half-sums, writes the 6 pooled groups in conv-input layout.
__global__ void k1_pool(const float* __restrict__ x, float* __restrict__ yin) {
    const int n = blockIdx.x >> 8;
    const int c = blockIdx.x & 255;
    __shared__ float tile[64][65];   // +1 pad: conflict-free column reads
    __shared__ float rs[64][2];      // row half-sums (w<32, w>=32)
    __shared__ float cs[2][64];      // col half-sums (h<32, h>=32)

    const int t = threadIdx.x;
    const float* xb = x + ((size_t)(n * CIN + c) << 12);   // 4096 floats

    const float4* x4 = (const float4*)xb;
#pragma unroll
    for (int i = 0; i < 4; ++i) {
        int idx  = i * 256 + t;        // float4 index 0..1023
        int row  = idx >> 4;
        int col4 = idx & 15;
        float4 v = x4[idx];
        tile[row][col4 * 4 + 0] = v.x;
        tile[row][col4 * 4 + 1] = v.y;
        tile[row][col4 * 4 + 2] = v.z;
        tile[row][col4 * 4 + 3] = v.w;
    }
    __syncthreads();

    if (t < 128) {
        int r = t >> 1, half = t & 1;
        float s = 0.f;
#pragma unroll
        for (int j = 0; j < 32; ++j) s += tile[r][half * 32 + j];
        rs[r][half] = s;
    } else {
        int t2 = t - 128;
        int w = t2 & 63, hh = t2 >> 6;
        float s = 0.f;
#pragma unroll
        for (int j = 0; j < 32; ++j) s += tile[hh * 32 + j][w];
        cs[hh][w] = s;
    }
    __syncthreads();

    if (t < 128) {
        int p = t;
        float g1, g2;
        if (p < 64) { g1 = rs[p][0];      g2 = rs[p][1]; }
        else        { g1 = cs[0][p - 64]; g2 = cs[1][p - 64]; }
        float g0 = (g1 + g2) * (1.f / 64.f);
        float* yb = yin + ((size_t)n * ICK + c) * PP + p;
        yb[0]                      = g0;
        yb[(size_t)256 * PP]       = g1 * (1.f / 32.f);
        yb[(size_t)512 * PP]       = g2 * (1.f / 32.f);
    }
}

// ---- Kernel 2a: partial 1-D dilated conv (center kw tap only) ----
// grid (n, o, chunk) = 32*8*8 = 2048 blocks. Each block: 96-IC partial sum
// for all 128 positions. partial[n][chunk][o][p].
__global__ void k2a_partial(const float* __restrict__ yin,
                            const float* __restrict__ w1,
                            float* __restrict__ partial) {
    const int b     = blockIdx.x;
    const int chunk = b & 7;
    const int o     = (b >> 3) & 7;
    const int n     = b >> 6;
    const int t     = threadIdx.x;

    __shared__ float Wl[96 * 3];
    __shared__ float part[2][128];

    // stage weights: kw=1 column of the 3x3 kernel only
    for (int i = t; i < 96 * 3; i += 256) {
        int icl = i / 3, kh = i - icl * 3;
        Wl[i] = w1[(size_t)o * (ICK * 9) + (size_t)(chunk * 96 + icl) * 9 + kh * 3 + 1];
    }
    __syncthreads();

    const int p   = t & 127;
    const int rep = t >> 7;
    const float* yb = yin + ((size_t)n * ICK + chunk * 96 + rep * 48) * PP;

    float acc = 0.f;
#pragma unroll 4
    for (int i = 0; i < 48; ++i) {
        const float* row = yb + (size_t)i * PP;
        const float* wr  = &Wl[(rep * 48 + i) * 3];
        float v0 = (p >= 2)   ? row[p - 2] : 0.f;
        float v1 = row[p];
        float v2 = (p < 126) ? row[p + 2] : 0.f;
        acc += wr[0] * v0 + wr[1] * v1 + wr[2] * v2;
    }

    part[rep][p] = acc;
    __syncthreads();
    if (t < 128) {
        partial[(((size_t)n * 8 + chunk) * 8 + o) * PP + t] = part[0][t] + part[1][t];
    }
}

// ---- Kernel 2r: reduce partials + BN + SiLU + SE mean/gate -> gated ysilu ----
// block per n (32 blocks).
__global__ void k2r_reduce(const float* __restrict__ partial,
                           const float* __restrict__ b1,
                           const float* __restrict__ gamma, const float* __restrict__ beta,
                           const float* __restrict__ bmean, const float* __restrict__ bvar,
                           const float* __restrict__ gw, const float* __restrict__ gb,
                           float* __restrict__ ysilu) {
    const int n = blockIdx.x;
    const int t = threadIdx.x;
    __shared__ float sm[8][129];   // +1 pad: conflict-free column sums
    __shared__ float seg[8];

    float sv[4];
#pragma unroll
    for (int k = 0; k < 4; ++k) {
        int idx = k * 256 + t;
        int o = idx >> 7, p = idx & 127;
        float s = 0.f;
#pragma unroll
        for (int ch = 0; ch < 8; ++ch)
            s += partial[(((size_t)n * 8 + ch) * 8 + o) * PP + p];
        float scale = gamma[o] * rsqrtf(bvar[o] + 1e-5f);
        float v = (s + b1[o] - bmean[o]) * scale + beta[o];
        float sl = v * sigmoidf_(v);
        sv[k] = sl;
        sm[o][p] = sl;
    }
    __syncthreads();
    if (t < 8) {
        float s = 0.f;
#pragma unroll
        for (int p = 0; p < 128; ++p) s += sm[t][p];
        seg[t] = sigmoidf_(gw[0] * (s * (1.f / 128.f)) + gb[0]);
    }
    __syncthreads();
#pragma unroll
    for (int k = 0; k < 4; ++k) {
        int idx = k * 256 + t;
        int o = idx >> 7, p = idx & 127;
        ysilu[((size_t)n * MIPC + o) * PP + p] = sv[k] * seg[o];
    }
}

// ------- Kernel 3: heads (a_h, a_w from ysilu) + out = x * a_h * a_w -------
// block per (n, c). ysilu slice (4 KB) is L2-broadcast to all 256 c-blocks.
__global__ void __launch_bounds__(256)
k3_apply(const float* __restrict__ x, const float* __restrict__ ygated,
         const float* __restrict__ chw, const float* __restrict__ chb,
         const float* __restrict__ cww, const float* __restrict__ cwb,
         float* __restrict__ out) {
    const int n = blockIdx.x >> 8;
    const int c = blockIdx.x & 255;
    const int t = threadIdx.x;
    __shared__ float yg[MIPC * PP];  // 1024 floats
    __shared__ float ah[64];
    __shared__ float aw[64];

    ((float4*)yg)[t] = ((const float4*)(ygated + (size_t)n * MIPC * PP))[t];
    __syncthreads();

    if (t < 64) {
        float a = chb[c];
#pragma unroll
        for (int m = 0; m < MIPC; ++m) a += chw[c * MIPC + m] * yg[m * PP + t];
        ah[t] = sigmoidf_(a);
    } else if (t < 128) {
        int h = t - 64;
        float a = cwb[c];
#pragma unroll
        for (int m = 0; m < MIPC; ++m) a += cww[c * MIPC + m] * yg[m * PP + 64 + h];
        aw[h] = sigmoidf_(a);
    }
    __syncthreads();

    size_t base = ((size_t)(n * CIN + c)) << 12;
    const float4* x4 = (const float4*)(x + base);
    float4* o4 = (float4*)(out + base);
    const float4* aw4 = (const float4*)aw;
#pragma unroll
    for (int i = 0; i < 4; ++i) {
        int idx  = i * 256 + t;
        int row  = idx >> 4;
        int col4 = idx & 15;
        float4 v = x4[idx];
        float a = ah[row];
        float4 wv = aw4[col4];
        v.x *= a * wv.x;
        v.y *= a * wv.y;
        v.z *= a * wv.z;
        v.w *= a * wv.w;
        o4[idx] = v;
    }
}

extern "C" void kernel_launch(void* const* d_in, const int* in_sizes, int n_in,
                              void* d_out, int out_size, void* d_ws, size_t ws_size,
                              hipStream_t stream) {
    const float* x     = (const float*)d_in[0];
    const float* w1    = (const float*)d_in[1];
    const float* b1    = (const float*)d_in[2];
    const float* gamma = (const float*)d_in[3];
    const float* beta  = (const float*)d_in[4];
    const float* bmean = (const float*)d_in[5];
    const float* bvar  = (const float*)d_in[6];
    const float* gw    = (const float*)d_in[7];
    const float* gb    = (const float*)d_in[8];
    const float* chw   = (const float*)d_in[9];
    const float* chb   = (const float*)d_in[10];
    const float* cww   = (const float*)d_in[11];
    const float* cwb   = (const float*)d_in[12];
    float* out = (float*)d_out;

    float* ws      = (float*)d_ws;
    float* yin     = ws;                                   // 32*768*128 = 3,145,728 f
    float* partial = yin + (size_t)NB * ICK * PP;          // 32*8*8*128 = 262,144 f
    float* ysilu   = partial + (size_t)NB * 8 * MIPC * PP; // 32*8*128   = 32,768 f

    k1_pool    <<<NB * CIN, 256, 0, stream>>>(x, yin);
    k2a_partial<<<NB * MIPC * 8, 256, 0, stream>>>(yin, w1, partial);
    k2r_reduce <<<NB, 256, 0, stream>>>(partial, b1, gamma, beta, bmean, bvar,
                                        gw, gb, ysilu);
    k3_apply   <<<NB * CIN, 256, 0, stream>>>(x, ysilu, chw, chb, cww, cwb, out);
}